// Round 2
// baseline (619.879 us; speedup 1.0000x reference)
//
#include <hip/hip_runtime.h>
#include <hip/hip_bf16.h>

// Problem: B=8, T_OUT=256, T_IN=512, L=128, D_IN=128, D_ATT=128
// Dtype of inputs/outputs resolved AT RUNTIME by a probe kernel (bf16 vs f32),
// because R1's NaN is consistent with reading f32 data as bf16.
// All internal math f32 in workspace.
//
// ws layout (float elements):
//   [0]       : int flag (1 = f32 data, 0 = bf16 data)
//   CV_*      : all 11 inputs converted to f32
//   XZ/KEYS/X : intermediates
#define CV_INP   256
#define CV_ATT   262400
#define CV_WK    786688
#define CV_WR    852224
#define CV_BIAS  917760
#define CV_W1    918272
#define CV_B1    934656
#define CV_W2    934784
#define CV_B2    951168
#define CV_W3    951296
#define CV_B3    951424
#define XZ_OFF   1048576
#define KEYS_OFF 2097152
#define X_OFF    2621440
// out layout: out(8,256,256) @0, h(8,128) @524288, c(8,128) @525312
#define OUT_H    524288
#define OUT_C    525312

__device__ __forceinline__ float fast_rcp(float x) { return __builtin_amdgcn_rcpf(x); }
__device__ __forceinline__ float fast_sig(float v) { return fast_rcp(1.f + __expf(-v)); }
__device__ __forceinline__ float fast_tanh(float v) { return 2.f * fast_rcp(1.f + __expf(-2.f * v)) - 1.f; }
__device__ __forceinline__ float bf2f(__hip_bfloat16 v) { return __bfloat162float(v); }

__device__ __forceinline__ void store_out(void* out, int idx, float v, int isf32) {
  if (isf32) ((float*)out)[idx] = v;
  else ((__hip_bfloat16*)out)[idx] = __float2bfloat16(v);
}

// ---------------- Kernel 0: dtype probe ----------------
// f32 data read as bf16 halves: low halves are ~uniform 16-bit -> exp==0xFF with P=2^-8
// (~256 hits in 131072). True bf16 data: zero NaN/Inf patterns.
__global__ __launch_bounds__(256)
void dtype_probe(const unsigned short* __restrict__ att_raw, int* __restrict__ flag) {
  __shared__ int cnt[256];
  const int tid = threadIdx.x;
  int local = 0;
  for (int i = tid; i < 131072; i += 256) {
    unsigned short u = att_raw[i];
    if (((u >> 7) & 0xFF) == 0xFF) local++;
  }
  cnt[tid] = local;
  __syncthreads();
  for (int s = 128; s > 0; s >>= 1) {
    if (tid < s) cnt[tid] += cnt[tid + s];
    __syncthreads();
  }
  if (tid == 0) *flag = (cnt[0] > 8) ? 1 : 0;
}

// ---------------- Kernel 1: convert all inputs to f32 in ws ----------------
__device__ __forceinline__ void conv_seg(const void* src, float* __restrict__ dst, int n,
                                         int isf32, int g, int gs) {
  if (isf32) {
    const float* s = (const float*)src;
    for (int i = g; i < n; i += gs) dst[i] = s[i];
  } else {
    const __hip_bfloat16* s = (const __hip_bfloat16*)src;
    for (int i = g; i < n; i += gs) dst[i] = bf2f(s[i]);
  }
}

__global__ __launch_bounds__(256)
void convert_all(const void* inp, const void* att, const void* wk, const void* wr,
                 const void* bias, const void* w1, const void* b1, const void* w2,
                 const void* b2p, const void* w3, const void* b3p, float* __restrict__ ws) {
  const int isf32 = ((const int*)ws)[0];
  const int g = blockIdx.x * 256 + threadIdx.x, gs = gridDim.x * 256;
  conv_seg(inp,  ws + CV_INP,  262144, isf32, g, gs);
  conv_seg(att,  ws + CV_ATT,  524288, isf32, g, gs);
  conv_seg(wk,   ws + CV_WK,   65536,  isf32, g, gs);
  conv_seg(wr,   ws + CV_WR,   65536,  isf32, g, gs);
  conv_seg(bias, ws + CV_BIAS, 512,    isf32, g, gs);
  conv_seg(w1,   ws + CV_W1,   16384,  isf32, g, gs);
  conv_seg(b1,   ws + CV_B1,   128,    isf32, g, gs);
  conv_seg(w2,   ws + CV_W2,   16384,  isf32, g, gs);
  conv_seg(b2p,  ws + CV_B2,   128,    isf32, g, gs);
  conv_seg(w3,   ws + CV_W3,   128,    isf32, g, gs);
  conv_seg(b3p,  ws + CV_B3,   1,      isf32, g, gs);
}

// ---------------- Kernel A: keys = attended @ W1 + b1  (4096 rows x 128) ----------------
__global__ __launch_bounds__(256)
void keys_gemm(const float* __restrict__ ws) {
  const float* att = ws + CV_ATT;
  const float* W1  = ws + CV_W1;
  const float* b1  = ws + CV_B1;
  float* keys = (float*)ws + KEYS_OFF;
  __shared__ float ar[16][128];
  const int tid = threadIdx.x;
  const int row0 = blockIdx.x * 16;
  for (int i = tid; i < 16 * 128; i += 256) ar[i >> 7][i & 127] = att[row0 * 128 + i];
  __syncthreads();
  const int l = tid & 127, r0 = tid >> 7;
  float acc[8];
  const float bl = b1[l];
#pragma unroll
  for (int i = 0; i < 8; ++i) acc[i] = bl;
  for (int d = 0; d < 128; d += 4) {
    float w0 = W1[(d + 0) * 128 + l], w1 = W1[(d + 1) * 128 + l];
    float w2 = W1[(d + 2) * 128 + l], w3 = W1[(d + 3) * 128 + l];
#pragma unroll
    for (int i = 0; i < 8; ++i) {
      float4 a4 = *(const float4*)&ar[r0 + 2 * i][d];
      acc[i] += a4.x * w0 + a4.y * w1 + a4.z * w2 + a4.w * w3;
    }
  }
#pragma unroll
  for (int i = 0; i < 8; ++i) keys[(row0 + r0 + 2 * i) * 128 + l] = acc[i];
}

// ---------------- Kernel B: xz = inputs @ Wk + bias  (2048 rows x 512) ----------------
__global__ __launch_bounds__(256)
void xz_gemm(const float* __restrict__ ws) {
  const float* in   = ws + CV_INP;
  const float* Wk   = ws + CV_WK;
  const float* bias = ws + CV_BIAS;
  float* xz = (float*)ws + XZ_OFF;
  __shared__ float ar[8][128];
  const int tid = threadIdx.x;
  const int row0 = blockIdx.x * 8;
  for (int i = tid; i < 8 * 128; i += 256) ar[i >> 7][i & 127] = in[row0 * 128 + i];
  __syncthreads();
  float acc[8][2];
  const float bb0 = bias[tid], bb1 = bias[tid + 256];
#pragma unroll
  for (int r = 0; r < 8; ++r) { acc[r][0] = bb0; acc[r][1] = bb1; }
  for (int d = 0; d < 128; d += 4) {
    float w0a = Wk[(d + 0) * 512 + tid], w0b = Wk[(d + 0) * 512 + tid + 256];
    float w1a = Wk[(d + 1) * 512 + tid], w1b = Wk[(d + 1) * 512 + tid + 256];
    float w2a = Wk[(d + 2) * 512 + tid], w2b = Wk[(d + 2) * 512 + tid + 256];
    float w3a = Wk[(d + 3) * 512 + tid], w3b = Wk[(d + 3) * 512 + tid + 256];
#pragma unroll
    for (int r = 0; r < 8; ++r) {
      float4 a4 = *(const float4*)&ar[r][d];
      acc[r][0] += a4.x * w0a + a4.y * w1a + a4.z * w2a + a4.w * w3a;
      acc[r][1] += a4.x * w0b + a4.y * w1b + a4.z * w2b + a4.w * w3b;
    }
  }
#pragma unroll
  for (int r = 0; r < 8; ++r) {
    xz[(row0 + r) * 512 + tid] = acc[r][0];
    xz[(row0 + r) * 512 + tid + 256] = acc[r][1];
  }
}

// ---------------- Kernel C: LSTM scan, 1 block per batch ----------------
__global__ __launch_bounds__(512, 2)
void lstm_scan(const float* __restrict__ ws, void* __restrict__ out) {
  const float* xz = ws + XZ_OFF;
  const float* Wr = ws + CV_WR;
  float* x = (float*)ws + X_OFF;
  const int isf32 = ((const int*)ws)[0];
  const int b = blockIdx.x;   // 0..7
  const int j = threadIdx.x;  // 0..511
  __shared__ float hbuf[128];
  __shared__ float zbuf[512];
  float wr[128];
#pragma unroll
  for (int k = 0; k < 128; ++k) wr[k] = Wr[k * 512 + j];
  if (j < 128) hbuf[j] = 0.f;
  float c = 0.f;
  __syncthreads();
  const float* xzb = xz + b * 256 * 512;
  float znext = xzb[j];  // prefetch t=0
  for (int t = 0; t < 256; ++t) {
    float a0 = 0.f, a1 = 0.f, a2 = 0.f, a3 = 0.f;
#pragma unroll
    for (int k = 0; k < 128; k += 4) {
      float4 h4 = *(const float4*)&hbuf[k];
      a0 += h4.x * wr[k + 0];
      a1 += h4.y * wr[k + 1];
      a2 += h4.z * wr[k + 2];
      a3 += h4.w * wr[k + 3];
    }
    float z = znext + (a0 + a1) + (a2 + a3);
    if (t < 255) znext = xzb[(t + 1) * 512 + j];
    zbuf[j] = z;
    __syncthreads();
    if (j < 128) {
      float si = fast_sig(zbuf[j]);
      float sf = fast_sig(zbuf[128 + j]);
      float tg = fast_tanh(zbuf[256 + j]);
      float so = fast_sig(zbuf[384 + j]);
      c = sf * c + si * tg;
      float h = so * fast_tanh(c);
      hbuf[j] = h;
      x[(b * 256 + t) * 128 + j] = h;
    }
    __syncthreads();
  }
  if (j < 128) {
    store_out(out, OUT_H + b * 128 + j, hbuf[j], isf32);
    store_out(out, OUT_C + b * 128 + j, c, isf32);
  }
}

// ---------------- Kernel D: qproj + scores + softmax + weighted + concat ----------------
__global__ __launch_bounds__(256)
void attn_out_k(const float* __restrict__ ws, void* __restrict__ out) {
  const float* keys = ws + KEYS_OFF;
  const float* attc = ws + CV_ATT;
  const float* x    = ws + X_OFF;
  const float* W2c  = ws + CV_W2;
  const float* b2c  = ws + CV_B2;
  const float* W3c  = ws + CV_W3;
  const float* b3c  = ws + CV_B3;
  const int isf32 = ((const int*)ws)[0];
  __shared__ float qp[8][128];
  __shared__ float xr[8][128];
  __shared__ float sc[8][512];
  __shared__ float kt[64][129];  // +1 pad: 2-way bank alias only (free per m136)
  __shared__ float w3s[128];
  const int tid = threadIdx.x;
  const int b = blockIdx.x >> 5, qt = blockIdx.x & 31;
  const int q0 = qt * 8;
  const int l = tid & 127, r0 = tid >> 7;
  if (tid < 128) w3s[tid] = W3c[tid];
  for (int i = tid; i < 8 * 128; i += 256) xr[i >> 7][i & 127] = x[(b * 256 + q0) * 128 + i];
  __syncthreads();
  // qproj = x @ W2 + b2 ; also copy x into out[:, :128]
  {
    float qa[4];
    const float bl = b2c[l];
#pragma unroll
    for (int i = 0; i < 4; ++i) qa[i] = bl;
    for (int d = 0; d < 128; d += 4) {
      float w0 = W2c[(d + 0) * 128 + l], w1 = W2c[(d + 1) * 128 + l];
      float w2v = W2c[(d + 2) * 128 + l], w3v = W2c[(d + 3) * 128 + l];
#pragma unroll
      for (int i = 0; i < 4; ++i) {
        float4 a4 = *(const float4*)&xr[r0 + 2 * i][d];
        qa[i] += a4.x * w0 + a4.y * w1 + a4.z * w2v + a4.w * w3v;
      }
    }
#pragma unroll
    for (int i = 0; i < 4; ++i) {
      int r = r0 + 2 * i;
      qp[r][l] = qa[i];
      store_out(out, (b * 256 + q0 + r) * 256 + l, xr[r][l], isf32);
    }
  }
  // scores[r][k] = sum_l tanh(keys[b,k,l] + qp[r][l]) * w3[l] + b3
  const float b3v = b3c[0];
  for (int kt0 = 0; kt0 < 512; kt0 += 64) {
    __syncthreads();  // prev tile consumed (and qp ready on first iter)
    for (int i = tid; i < 64 * 128; i += 256)
      kt[i >> 7][i & 127] = keys[(b * 512 + kt0 + (i >> 7)) * 128 + (i & 127)];
    __syncthreads();
#pragma unroll
    for (int pp = 0; pp < 2; ++pp) {
      const int p = tid + pp * 256;
      const int r = p >> 6, k = p & 63;
      float acc = 0.f;
      for (int ll = 0; ll < 128; ll += 4) {
        float4 q4 = *(const float4*)&qp[r][ll];
        float4 w4 = *(const float4*)&w3s[ll];
        acc += fast_tanh(kt[k][ll + 0] + q4.x) * w4.x
             + fast_tanh(kt[k][ll + 1] + q4.y) * w4.y
             + fast_tanh(kt[k][ll + 2] + q4.z) * w4.z
             + fast_tanh(kt[k][ll + 3] + q4.w) * w4.w;
      }
      sc[r][kt0 + k] = acc + b3v;
    }
  }
  __syncthreads();
  // softmax: wave w owns rows {w, w+4}; in-wave shuffle reductions
  {
    const int wave = tid >> 6, lane = tid & 63;
    for (int r = wave; r < 8; r += 4) {
      float v[8];
#pragma unroll
      for (int i = 0; i < 8; ++i) v[i] = sc[r][lane + i * 64];
      float m = v[0];
#pragma unroll
      for (int i = 1; i < 8; ++i) m = fmaxf(m, v[i]);
#pragma unroll
      for (int off = 32; off > 0; off >>= 1) m = fmaxf(m, __shfl_xor(m, off));
      float e[8], s = 0.f;
#pragma unroll
      for (int i = 0; i < 8; ++i) { e[i] = __expf(v[i] - m); s += e[i]; }
#pragma unroll
      for (int off = 32; off > 0; off >>= 1) s += __shfl_xor(s, off);
      const float inv = fast_rcp(s);
#pragma unroll
      for (int i = 0; i < 8; ++i) sc[r][lane + i * 64] = e[i] * inv;
    }
  }
  __syncthreads();
  // weighted[r][l] = sum_k attn[r][k] * attended[b,k,l]
  {
    const float* attb = attc + b * 512 * 128;
    float wa[4] = {0.f, 0.f, 0.f, 0.f};
    for (int k = 0; k < 512; k += 4) {
      float a0 = attb[(k + 0) * 128 + l];
      float a1 = attb[(k + 1) * 128 + l];
      float a2 = attb[(k + 2) * 128 + l];
      float a3 = attb[(k + 3) * 128 + l];
#pragma unroll
      for (int i = 0; i < 4; ++i) {
        float4 p4 = *(const float4*)&sc[r0 + 2 * i][k];
        wa[i] += p4.x * a0 + p4.y * a1 + p4.z * a2 + p4.w * a3;
      }
    }
#pragma unroll
    for (int i = 0; i < 4; ++i)
      store_out(out, (b * 256 + q0 + r0 + 2 * i) * 256 + 128 + l, wa[i], isf32);
  }
}

extern "C" void kernel_launch(void* const* d_in, const int* in_sizes, int n_in,
                              void* d_out, int out_size, void* d_ws, size_t ws_size,
                              hipStream_t stream) {
  float* ws = (float*)d_ws;
  hipLaunchKernelGGL(dtype_probe, dim3(1), dim3(256), 0, stream,
                     (const unsigned short*)d_in[1], (int*)d_ws);
  hipLaunchKernelGGL(convert_all, dim3(512), dim3(256), 0, stream,
                     d_in[0], d_in[1], d_in[2], d_in[3], d_in[4], d_in[5], d_in[6],
                     d_in[7], d_in[8], d_in[9], d_in[10], ws);
  hipLaunchKernelGGL(keys_gemm, dim3(256), dim3(256), 0, stream, ws);
  hipLaunchKernelGGL(xz_gemm,   dim3(256), dim3(256), 0, stream, ws);
  hipLaunchKernelGGL(lstm_scan, dim3(8),   dim3(512), 0, stream, ws, d_out);
  hipLaunchKernelGGL(attn_out_k, dim3(256), dim3(256), 0, stream, ws, d_out);
}

// Round 3
// 528.151 us; speedup vs baseline: 1.1737x; 1.1737x over previous
//
#include <hip/hip_runtime.h>
#include <hip/hip_bf16.h>

// Problem: B=8, T_OUT=256, T_IN=512, L=128, D_IN=128, D_ATT=128
// Inputs proven f32 at runtime by probe (R2 passed); probe kept for robustness.
// All internal math f32 (dot-products vs f16-quantized h/Wr in the scan).
//
// ws layout (float elements):
#define CV_INP   256
#define CV_ATT   262400
#define CV_WK    786688
#define CV_WR    852224
#define CV_BIAS  917760
#define CV_W1    918272
#define CV_B1    934656
#define CV_W2    934784
#define CV_B2    951168
#define CV_W3    951296
#define CV_B3    951424
#define XZ_OFF   1048576
#define KEYS_OFF 2097152
#define X_OFF    2621440
// out layout: out(8,256,256) @0, h(8,128) @524288, c(8,128) @525312
#define OUT_H    524288
#define OUT_C    525312

typedef _Float16 half2v __attribute__((ext_vector_type(2)));

__device__ __forceinline__ float fast_rcp(float x) { return __builtin_amdgcn_rcpf(x); }
__device__ __forceinline__ float fast_sig(float v) { return fast_rcp(1.f + __expf(-v)); }
__device__ __forceinline__ float fast_tanh(float v) { return 2.f * fast_rcp(1.f + __expf(-2.f * v)) - 1.f; }
__device__ __forceinline__ float bf2f(__hip_bfloat16 v) { return __bfloat162float(v); }

__device__ __forceinline__ float dot2acc(unsigned hbits, unsigned wbits, float acc) {
#if __has_builtin(__builtin_amdgcn_fdot2)
  half2v h = *(half2v*)&hbits, w = *(half2v*)&wbits;
  return __builtin_amdgcn_fdot2(h, w, acc, false);
#else
  half2v h = *(half2v*)&hbits, w = *(half2v*)&wbits;
  return acc + (float)h.x * (float)w.x + (float)h.y * (float)w.y;
#endif
}

__device__ __forceinline__ void store_out(void* out, int idx, float v, int isf32) {
  if (isf32) ((float*)out)[idx] = v;
  else ((__hip_bfloat16*)out)[idx] = __float2bfloat16(v);
}

// ---------------- Kernel 0: dtype probe ----------------
// f32 read as u16 halves: low halves ~uniform -> exp-field==0xFF with P=2^-8
// (~64 hits in 32768). True bf16 normal data: 0 hits.
__global__ __launch_bounds__(256)
void dtype_probe(const unsigned short* __restrict__ att_raw, int* __restrict__ flag) {
  __shared__ int cnt[256];
  const int tid = threadIdx.x;
  int local = 0;
  for (int i = tid; i < 32768; i += 256) {
    unsigned short u = att_raw[i];
    if (((u >> 7) & 0xFF) == 0xFF) local++;
  }
  cnt[tid] = local;
  __syncthreads();
  for (int s = 128; s > 0; s >>= 1) {
    if (tid < s) cnt[tid] += cnt[tid + s];
    __syncthreads();
  }
  if (tid == 0) *flag = (cnt[0] > 8) ? 1 : 0;
}

// ---------------- Kernel 1: convert all inputs to f32 in ws ----------------
__device__ __forceinline__ void conv_seg(const void* src, float* __restrict__ dst, int n,
                                         int isf32, int g, int gs) {
  if (isf32) {
    const float* s = (const float*)src;
    for (int i = g; i < n; i += gs) dst[i] = s[i];
  } else {
    const __hip_bfloat16* s = (const __hip_bfloat16*)src;
    for (int i = g; i < n; i += gs) dst[i] = bf2f(s[i]);
  }
}

__global__ __launch_bounds__(256)
void convert_all(const void* inp, const void* att, const void* wk, const void* wr,
                 const void* bias, const void* w1, const void* b1, const void* w2,
                 const void* b2p, const void* w3, const void* b3p, float* __restrict__ ws) {
  const int isf32 = ((const int*)ws)[0];
  const int g = blockIdx.x * 256 + threadIdx.x, gs = gridDim.x * 256;
  conv_seg(inp,  ws + CV_INP,  262144, isf32, g, gs);
  conv_seg(att,  ws + CV_ATT,  524288, isf32, g, gs);
  conv_seg(wk,   ws + CV_WK,   65536,  isf32, g, gs);
  conv_seg(wr,   ws + CV_WR,   65536,  isf32, g, gs);
  conv_seg(bias, ws + CV_BIAS, 512,    isf32, g, gs);
  conv_seg(w1,   ws + CV_W1,   16384,  isf32, g, gs);
  conv_seg(b1,   ws + CV_B1,   128,    isf32, g, gs);
  conv_seg(w2,   ws + CV_W2,   16384,  isf32, g, gs);
  conv_seg(b2p,  ws + CV_B2,   128,    isf32, g, gs);
  conv_seg(w3,   ws + CV_W3,   128,    isf32, g, gs);
  conv_seg(b3p,  ws + CV_B3,   1,      isf32, g, gs);
}

// ---------------- Kernel A: keys = attended @ W1 + b1  (4096 rows x 128) ----------------
__global__ __launch_bounds__(256)
void keys_gemm(const float* __restrict__ ws) {
  const float* att = ws + CV_ATT;
  const float* W1  = ws + CV_W1;
  const float* b1  = ws + CV_B1;
  float* keys = (float*)ws + KEYS_OFF;
  __shared__ float ar[16][128];
  const int tid = threadIdx.x;
  const int row0 = blockIdx.x * 16;
  for (int i = tid; i < 16 * 128; i += 256) ar[i >> 7][i & 127] = att[row0 * 128 + i];
  __syncthreads();
  const int l = tid & 127, r0 = tid >> 7;
  float acc[8];
  const float bl = b1[l];
#pragma unroll
  for (int i = 0; i < 8; ++i) acc[i] = bl;
  for (int d = 0; d < 128; d += 4) {
    float w0 = W1[(d + 0) * 128 + l], w1 = W1[(d + 1) * 128 + l];
    float w2 = W1[(d + 2) * 128 + l], w3 = W1[(d + 3) * 128 + l];
#pragma unroll
    for (int i = 0; i < 8; ++i) {
      float4 a4 = *(const float4*)&ar[r0 + 2 * i][d];
      acc[i] += a4.x * w0 + a4.y * w1 + a4.z * w2 + a4.w * w3;
    }
  }
#pragma unroll
  for (int i = 0; i < 8; ++i) keys[(row0 + r0 + 2 * i) * 128 + l] = acc[i];
}

// ---------------- Kernel B: xz = inputs @ Wk + bias  (2048 rows x 512) ----------------
__global__ __launch_bounds__(256)
void xz_gemm(const float* __restrict__ ws) {
  const float* in   = ws + CV_INP;
  const float* Wk   = ws + CV_WK;
  const float* bias = ws + CV_BIAS;
  float* xz = (float*)ws + XZ_OFF;
  __shared__ float ar[8][128];
  const int tid = threadIdx.x;
  const int row0 = blockIdx.x * 8;
  for (int i = tid; i < 8 * 128; i += 256) ar[i >> 7][i & 127] = in[row0 * 128 + i];
  __syncthreads();
  float acc[8][2];
  const float bb0 = bias[tid], bb1 = bias[tid + 256];
#pragma unroll
  for (int r = 0; r < 8; ++r) { acc[r][0] = bb0; acc[r][1] = bb1; }
  for (int d = 0; d < 128; d += 4) {
    float w0a = Wk[(d + 0) * 512 + tid], w0b = Wk[(d + 0) * 512 + tid + 256];
    float w1a = Wk[(d + 1) * 512 + tid], w1b = Wk[(d + 1) * 512 + tid + 256];
    float w2a = Wk[(d + 2) * 512 + tid], w2b = Wk[(d + 2) * 512 + tid + 256];
    float w3a = Wk[(d + 3) * 512 + tid], w3b = Wk[(d + 3) * 512 + tid + 256];
#pragma unroll
    for (int r = 0; r < 8; ++r) {
      float4 a4 = *(const float4*)&ar[r][d];
      acc[r][0] += a4.x * w0a + a4.y * w1a + a4.z * w2a + a4.w * w3a;
      acc[r][1] += a4.x * w0b + a4.y * w1b + a4.z * w2b + a4.w * w3b;
    }
  }
#pragma unroll
  for (int r = 0; r < 8; ++r) {
    xz[(row0 + r) * 512 + tid] = acc[r][0];
    xz[(row0 + r) * 512 + tid + 256] = acc[r][1];
  }
}

// ---------------- Kernel C: LSTM scan v2 ----------------
// 1 block/batch, 128 threads. Thread j owns gate columns {j, j+128, j+256, j+384}
// = (i,f,g,o) for unit j -> gate math thread-local, no zbuf, 1 barrier/step.
// Wr packed f16x2 in 256 VGPRs, consumed by v_dot2_f32_f16.
// h broadcast as packed-f16 LDS (256B): 16 ds_read_b128 per wave per step.
__global__ __launch_bounds__(128, 1)
void lstm_scan(const float* __restrict__ ws, void* __restrict__ out) {
  const float* xz = ws + XZ_OFF;
  const float* Wr = ws + CV_WR;
  float* x = (float*)ws + X_OFF;
  const int isf32 = ((const int*)ws)[0];
  const int b = blockIdx.x;   // 0..7
  const int j = threadIdx.x;  // 0..127
  __shared__ unsigned hb[2][64];  // h as packed f16 pairs, double-buffered

  // Pack Wr columns {j + 128c} into f16x2 registers: wr[c][k2] = (Wr[2k2][col], Wr[2k2+1][col])
  unsigned wr[4][64];
#pragma unroll
  for (int c = 0; c < 4; ++c) {
    const int col = j + 128 * c;
#pragma unroll
    for (int k2 = 0; k2 < 64; ++k2) {
      half2v w2 = { (_Float16)Wr[(2 * k2) * 512 + col], (_Float16)Wr[(2 * k2 + 1) * 512 + col] };
      wr[c][k2] = *(unsigned*)&w2;
    }
  }
  if (j < 64) hb[0][j] = 0u;  // h0 = 0
  float cst = 0.f;
  const float* xzb = xz + b * 256 * 512;
  float z0 = xzb[j], z1 = xzb[j + 128], z2 = xzb[j + 256], z3 = xzb[j + 384];
  __syncthreads();

  float hval = 0.f;
  for (int t = 0; t < 256; ++t) {
    const unsigned* hcur = hb[t & 1];
    float a0 = 0.f, a1 = 0.f, a2 = 0.f, a3 = 0.f;
    float e0 = 0.f, e1 = 0.f, e2 = 0.f, e3 = 0.f;
#pragma unroll
    for (int i = 0; i < 16; ++i) {
      uint4 hv = ((const uint4*)hcur)[i];
      a0 = dot2acc(hv.x, wr[0][4 * i + 0], a0);
      a1 = dot2acc(hv.x, wr[1][4 * i + 0], a1);
      a2 = dot2acc(hv.x, wr[2][4 * i + 0], a2);
      a3 = dot2acc(hv.x, wr[3][4 * i + 0], a3);
      e0 = dot2acc(hv.y, wr[0][4 * i + 1], e0);
      e1 = dot2acc(hv.y, wr[1][4 * i + 1], e1);
      e2 = dot2acc(hv.y, wr[2][4 * i + 1], e2);
      e3 = dot2acc(hv.y, wr[3][4 * i + 1], e3);
      a0 = dot2acc(hv.z, wr[0][4 * i + 2], a0);
      a1 = dot2acc(hv.z, wr[1][4 * i + 2], a1);
      a2 = dot2acc(hv.z, wr[2][4 * i + 2], a2);
      a3 = dot2acc(hv.z, wr[3][4 * i + 2], a3);
      e0 = dot2acc(hv.w, wr[0][4 * i + 3], e0);
      e1 = dot2acc(hv.w, wr[1][4 * i + 3], e1);
      e2 = dot2acc(hv.w, wr[2][4 * i + 3], e2);
      e3 = dot2acc(hv.w, wr[3][4 * i + 3], e3);
    }
    const float zi = z0 + a0 + e0, zf = z1 + a1 + e1;
    const float zg = z2 + a2 + e2, zo = z3 + a3 + e3;
    if (t < 255) {
      const float* nxt = xzb + (t + 1) * 512;
      z0 = nxt[j]; z1 = nxt[j + 128]; z2 = nxt[j + 256]; z3 = nxt[j + 384];
    }
    cst = fast_sig(zf) * cst + fast_sig(zi) * fast_tanh(zg);
    hval = fast_sig(zo) * fast_tanh(cst);
    // publish h for next step (other buffer) + persist x
    ((_Float16*)hb[(t + 1) & 1])[j] = (_Float16)hval;
    x[(b * 256 + t) * 128 + j] = hval;
    __syncthreads();
  }
  store_out(out, OUT_H + b * 128 + j, hval, isf32);
  store_out(out, OUT_C + b * 128 + j, cst, isf32);
}

// ---------------- Kernel D: qproj + scores + softmax + weighted + concat ----------------
__global__ __launch_bounds__(256)
void attn_out_k(const float* __restrict__ ws, void* __restrict__ out) {
  const float* keys = ws + KEYS_OFF;
  const float* attc = ws + CV_ATT;
  const float* x    = ws + X_OFF;
  const float* W2c  = ws + CV_W2;
  const float* b2c  = ws + CV_B2;
  const float* W3c  = ws + CV_W3;
  const float* b3c  = ws + CV_B3;
  const int isf32 = ((const int*)ws)[0];
  __shared__ float qp[8][128];
  __shared__ float xr[8][128];
  __shared__ float sc[8][512];
  __shared__ float kt[64][129];  // +1 pad: 2-way bank alias only (free per m136)
  __shared__ float w3s[128];
  const int tid = threadIdx.x;
  const int b = blockIdx.x >> 5, qt = blockIdx.x & 31;
  const int q0 = qt * 8;
  const int l = tid & 127, r0 = tid >> 7;
  if (tid < 128) w3s[tid] = W3c[tid];
  for (int i = tid; i < 8 * 128; i += 256) xr[i >> 7][i & 127] = x[(b * 256 + q0) * 128 + i];
  __syncthreads();
  // qproj = x @ W2 + b2 ; also copy x into out[:, :128]
  {
    float qa[4];
    const float bl = b2c[l];
#pragma unroll
    for (int i = 0; i < 4; ++i) qa[i] = bl;
    for (int d = 0; d < 128; d += 4) {
      float w0 = W2c[(d + 0) * 128 + l], w1 = W2c[(d + 1) * 128 + l];
      float w2v = W2c[(d + 2) * 128 + l], w3v = W2c[(d + 3) * 128 + l];
#pragma unroll
      for (int i = 0; i < 4; ++i) {
        float4 a4 = *(const float4*)&xr[r0 + 2 * i][d];
        qa[i] += a4.x * w0 + a4.y * w1 + a4.z * w2v + a4.w * w3v;
      }
    }
#pragma unroll
    for (int i = 0; i < 4; ++i) {
      int r = r0 + 2 * i;
      qp[r][l] = qa[i];
      store_out(out, (b * 256 + q0 + r) * 256 + l, xr[r][l], isf32);
    }
  }
  // scores[r][k] = sum_l tanh(keys[b,k,l] + qp[r][l]) * w3[l] + b3
  const float b3v = b3c[0];
  for (int kt0 = 0; kt0 < 512; kt0 += 64) {
    __syncthreads();  // prev tile consumed (and qp ready on first iter)
    for (int i = tid; i < 64 * 128; i += 256)
      kt[i >> 7][i & 127] = keys[(b * 512 + kt0 + (i >> 7)) * 128 + (i & 127)];
    __syncthreads();
#pragma unroll
    for (int pp = 0; pp < 2; ++pp) {
      const int p = tid + pp * 256;
      const int r = p >> 6, k = p & 63;
      float acc = 0.f;
      for (int ll = 0; ll < 128; ll += 4) {
        float4 q4 = *(const float4*)&qp[r][ll];
        float4 w4 = *(const float4*)&w3s[ll];
        acc += fast_tanh(kt[k][ll + 0] + q4.x) * w4.x
             + fast_tanh(kt[k][ll + 1] + q4.y) * w4.y
             + fast_tanh(kt[k][ll + 2] + q4.z) * w4.z
             + fast_tanh(kt[k][ll + 3] + q4.w) * w4.w;
      }
      sc[r][kt0 + k] = acc + b3v;
    }
  }
  __syncthreads();
  // softmax: wave w owns rows {w, w+4}; in-wave shuffle reductions
  {
    const int wave = tid >> 6, lane = tid & 63;
    for (int r = wave; r < 8; r += 4) {
      float v[8];
#pragma unroll
      for (int i = 0; i < 8; ++i) v[i] = sc[r][lane + i * 64];
      float m = v[0];
#pragma unroll
      for (int i = 1; i < 8; ++i) m = fmaxf(m, v[i]);
#pragma unroll
      for (int off = 32; off > 0; off >>= 1) m = fmaxf(m, __shfl_xor(m, off));
      float e[8], s = 0.f;
#pragma unroll
      for (int i = 0; i < 8; ++i) { e[i] = __expf(v[i] - m); s += e[i]; }
#pragma unroll
      for (int off = 32; off > 0; off >>= 1) s += __shfl_xor(s, off);
      const float inv = fast_rcp(s);
#pragma unroll
      for (int i = 0; i < 8; ++i) sc[r][lane + i * 64] = e[i] * inv;
    }
  }
  __syncthreads();
  // weighted[r][l] = sum_k attn[r][k] * attended[b,k,l]
  {
    const float* attb = attc + b * 512 * 128;
    float wa[4] = {0.f, 0.f, 0.f, 0.f};
    for (int k = 0; k < 512; k += 4) {
      float a0 = attb[(k + 0) * 128 + l];
      float a1 = attb[(k + 1) * 128 + l];
      float a2 = attb[(k + 2) * 128 + l];
      float a3 = attb[(k + 3) * 128 + l];
#pragma unroll
      for (int i = 0; i < 4; ++i) {
        float4 p4 = *(const float4*)&sc[r0 + 2 * i][k];
        wa[i] += p4.x * a0 + p4.y * a1 + p4.z * a2 + p4.w * a3;
      }
    }
#pragma unroll
    for (int i = 0; i < 4; ++i)
      store_out(out, (b * 256 + q0 + r0 + 2 * i) * 256 + 128 + l, wa[i], isf32);
  }
}

extern "C" void kernel_launch(void* const* d_in, const int* in_sizes, int n_in,
                              void* d_out, int out_size, void* d_ws, size_t ws_size,
                              hipStream_t stream) {
  float* ws = (float*)d_ws;
  hipLaunchKernelGGL(dtype_probe, dim3(1), dim3(256), 0, stream,
                     (const unsigned short*)d_in[1], (int*)d_ws);
  hipLaunchKernelGGL(convert_all, dim3(512), dim3(256), 0, stream,
                     d_in[0], d_in[1], d_in[2], d_in[3], d_in[4], d_in[5], d_in[6],
                     d_in[7], d_in[8], d_in[9], d_in[10], ws);
  hipLaunchKernelGGL(keys_gemm, dim3(256), dim3(256), 0, stream, ws);
  hipLaunchKernelGGL(xz_gemm,   dim3(256), dim3(256), 0, stream, ws);
  hipLaunchKernelGGL(lstm_scan, dim3(8),   dim3(128), 0, stream, ws, d_out);
  hipLaunchKernelGGL(attn_out_k, dim3(256), dim3(256), 0, stream, ws, d_out);
}